// Round 1
// baseline (156.661 us; speedup 1.0000x reference)
//
#include <hip/hip_runtime.h>
#include <math.h>

#define HH 768
#define WW 1024
#define HW (HH * WW)
#define NTAPS 5
#define F_EPS 1.1920929e-07f

__global__ __launch_bounds__(256) void fab_kernel(
    const float* __restrict__ x,
    const float* __restrict__ tangent,
    const float* __restrict__ sigmaD,
    const float* __restrict__ sigmaR,
    float* __restrict__ out,
    int npix)
{
    int idx = blockIdx.x * blockDim.x + threadIdx.x;
    if (idx >= npix) return;
    int b = idx / HW;
    int p = idx - b * HW;
    int h = p / WW;
    int w = p - h * WW;

    const float* xb = x + (size_t)b * 3 * HW;

    float tx = tangent[(size_t)b * 2 * HW + p];
    float ty = tangent[(size_t)b * 2 * HW + HW + p];
    float me = fmaxf(fabsf(tx), fabsf(ty));
    float ds = (me > 0.0f) ? (1.0f / me) : 1.0f;
    float dir_u = tx / (float)WW;
    float dir_v = ty / (float)HH;

    float sD = sigmaD[b];
    float sR = sigmaR[b];
    float two_sD2 = 2.0f * sD * sD;
    float two_sR2 = 2.0f * sR * sR;
    float half_step = 2.0f * sD;
    float den_D = two_sD2 + F_EPS;
    float den_R = two_sR2 + F_EPS;

    float base_u = ((float)w + 0.5f) / (float)WW;
    float base_v = ((float)h + 0.5f) / (float)HH;

    float c0c = xb[p];
    float c1c = xb[HW + p];
    float c2c = xb[2 * HW + p];

    float acc0 = c0c, acc1 = c1c, acc2 = c2c;
    float norm = 1.0f;

#pragma unroll
    for (int t = 0; t < NTAPS; ++t) {
        float it1 = (float)(2 * t + 1);
        float it2 = (float)(2 * t + 2);
        float itr1 = ds * it1;
        float itr2 = ds * it2;
        // kernelD == 0 exactly when |itr1| > half_step -> contribution is exactly 0
        if (fabsf(itr1) > half_step) continue;
        float kD1 = expf(-(itr1 * itr1) / den_D);
        float kD2 = expf(-(itr2 * itr2) / den_D);
        float kernelD = kD1 + kD2;
        float itr_d = (itr1 * kD1 + itr2 * kD2) / (kernelD + F_EPS);
        float ou = itr_d * dir_u;
        float ov = itr_d * dir_v;

#pragma unroll
        for (int s = 0; s < 2; ++s) {
            float u = (s == 0) ? (base_u + ou) : (base_u - ou);
            float v = (s == 0) ? (base_v + ov) : (base_v - ov);
            float xp = u * (float)WW - 0.5f;
            float yp = v * (float)HH - 0.5f;
            float x0f = floorf(xp);
            float y0f = floorf(yp);
            float fx = xp - x0f;
            float fy = yp - y0f;
            int x0i = min(max((int)x0f, 0), WW - 1);
            int x1i = min(max((int)x0f + 1, 0), WW - 1);
            int y0i = min(max((int)y0f, 0), HH - 1);
            int y1i = min(max((int)y0f + 1, 0), HH - 1);
            int i00 = y0i * WW + x0i;
            int i01 = y0i * WW + x1i;
            int i10 = y1i * WW + x0i;
            int i11 = y1i * WW + x1i;

            // channel 0
            float a00 = xb[i00], a01 = xb[i01], a10 = xb[i10], a11 = xb[i11];
            float top0 = a00 * (1.0f - fx) + a01 * fx;
            float bot0 = a10 * (1.0f - fx) + a11 * fx;
            float s0 = top0 * (1.0f - fy) + bot0 * fy;
            // channel 1
            float b00 = xb[HW + i00], b01 = xb[HW + i01], b10 = xb[HW + i10], b11 = xb[HW + i11];
            float top1 = b00 * (1.0f - fx) + b01 * fx;
            float bot1 = b10 * (1.0f - fx) + b11 * fx;
            float s1 = top1 * (1.0f - fy) + bot1 * fy;
            // channel 2
            float d00 = xb[2 * HW + i00], d01 = xb[2 * HW + i01], d10 = xb[2 * HW + i10], d11 = xb[2 * HW + i11];
            float top2 = d00 * (1.0f - fx) + d01 * fx;
            float bot2 = d10 * (1.0f - fx) + d11 * fx;
            float s2 = top2 * (1.0f - fy) + bot2 * fy;

            float cc0 = (s0 - c0c) * 100.0f;
            float cc1 = (s1 - c1c) * 254.0f;
            float cc2 = (s2 - c2c) * 254.0f;
            float e2 = fmaxf(cc0 * cc0 + cc1 * cc1 + cc2 * cc2, 1e-30f);
            float e = sqrtf(e2);
            float kE = expf(-(e * e) / den_R);
            float wgt = kernelD * kE;
            norm += wgt;
            acc0 += wgt * s0;
            acc1 += wgt * s1;
            acc2 += wgt * s2;
        }
    }

    size_t ob = (size_t)b * 3 * HW;
    out[ob + p] = acc0 / norm;
    out[ob + HW + p] = acc1 / norm;
    out[ob + 2 * HW + p] = acc2 / norm;
}

extern "C" void kernel_launch(void* const* d_in, const int* in_sizes, int n_in,
                              void* d_out, int out_size, void* d_ws, size_t ws_size,
                              hipStream_t stream) {
    const float* x = (const float*)d_in[0];
    const float* tangent = (const float*)d_in[1];
    const float* sigmaD = (const float*)d_in[2];
    const float* sigmaR = (const float*)d_in[3];
    float* out = (float*)d_out;

    int bs = in_sizes[2];           // sigmaD has one entry per batch
    int npix = bs * HW;
    int block = 256;
    int grid = (npix + block - 1) / block;
    fab_kernel<<<grid, block, 0, stream>>>(x, tangent, sigmaD, sigmaR, out, npix);
}

// Round 2
// 85.295 us; speedup vs baseline: 1.8367x; 1.8367x over previous
//
#include <hip/hip_runtime.h>
#include <math.h>

#define HH 768
#define WW 1024
#define HW (HH * WW)
#define NTAPS 5
#define F_EPS 1.1920929e-07f

// ---------------- pack kernel: planar RGB -> float4 ----------------
__global__ __launch_bounds__(256) void pack_kernel(
    const float* __restrict__ x, float4* __restrict__ xp, int npix)
{
    int i = blockIdx.x * blockDim.x + threadIdx.x;
    if (i >= npix) return;
    int b = i / HW;
    int p = i - b * HW;
    const float* xb = x + (size_t)b * 3 * HW;
    float4 v;
    v.x = xb[p];
    v.y = xb[HW + p];
    v.z = xb[2 * HW + p];
    v.w = 0.0f;
    xp[i] = v;
}

// ---------------- main kernel (packed float4 image) ----------------
__global__ __launch_bounds__(256) void fab_kernel4(
    const float4* __restrict__ xp4,
    const float* __restrict__ tangent,
    const float* __restrict__ sigmaD,
    const float* __restrict__ sigmaR,
    float* __restrict__ out,
    int npix)
{
    int idx = blockIdx.x * blockDim.x + threadIdx.x;
    if (idx >= npix) return;
    int b = idx / HW;
    int p = idx - b * HW;
    int h = p / WW;
    int w = p - h * WW;

    const float4* xb = xp4 + (size_t)b * HW;

    float tx = tangent[(size_t)b * 2 * HW + p];
    float ty = tangent[(size_t)b * 2 * HW + HW + p];
    float me = fmaxf(fabsf(tx), fabsf(ty));
    float ds = (me > 0.0f) ? (1.0f / me) : 1.0f;

    float sD = sigmaD[b];
    float sR = sigmaR[b];
    float half_step = 2.0f * sD;
    float nD = -1.0f / (2.0f * sD * sD + F_EPS);   // -1/den_D
    float nR = -1.0f / (2.0f * sR * sR + F_EPS);   // -1/den_R

    float4 c = xb[p];
    float acc0 = c.x, acc1 = c.y, acc2 = c.z;
    float norm = 1.0f;

#pragma unroll
    for (int t = 0; t < NTAPS; ++t) {
        float it1 = (float)(2 * t + 1);
        float it2 = (float)(2 * t + 2);
        float itr1 = ds * it1;
        float itr2 = ds * it2;
        // kernelD == 0 exactly when |itr1| > half_step -> contribution is exactly 0
        if (fabsf(itr1) > half_step) continue;
        float kD1 = __expf(itr1 * itr1 * nD);
        float kD2 = __expf(itr2 * itr2 * nD);
        float kernelD = kD1 + kD2;
        float itr_d = (itr1 * kD1 + itr2 * kD2) / (kernelD + F_EPS);
        float ox = itr_d * tx;   // == itr_d * (tx/W) * W up to rounding
        float oy = itr_d * ty;

#pragma unroll
        for (int s = 0; s < 2; ++s) {
            float xpf = (s == 0) ? ((float)w + ox) : ((float)w - ox);
            float ypf = (s == 0) ? ((float)h + oy) : ((float)h - oy);
            float x0f = floorf(xpf);
            float y0f = floorf(ypf);
            float fx = xpf - x0f;
            float fy = ypf - y0f;
            int x0i = min(max((int)x0f, 0), WW - 1);
            int x1i = min(max((int)x0f + 1, 0), WW - 1);
            int y0i = min(max((int)y0f, 0), HH - 1);
            int y1i = min(max((int)y0f + 1, 0), HH - 1);
            int r0 = y0i * WW;
            int r1 = y1i * WW;

            float4 q00 = xb[r0 + x0i];
            float4 q01 = xb[r0 + x1i];
            float4 q10 = xb[r1 + x0i];
            float4 q11 = xb[r1 + x1i];

            float gx = 1.0f - fx;
            float gy = 1.0f - fy;
            float s0 = (q00.x * gx + q01.x * fx) * gy + (q10.x * gx + q11.x * fx) * fy;
            float s1 = (q00.y * gx + q01.y * fx) * gy + (q10.y * gx + q11.y * fx) * fy;
            float s2 = (q00.z * gx + q01.z * fx) * gy + (q10.z * gx + q11.z * fx) * fy;

            float cc0 = (s0 - c.x) * 100.0f;
            float cc1 = (s1 - c.y) * 254.0f;
            float cc2 = (s2 - c.z) * 254.0f;
            float e2 = fmaxf(cc0 * cc0 + cc1 * cc1 + cc2 * cc2, 1e-30f);
            float kE = __expf(e2 * nR);          // == exp(-sqrt(e2)^2/den) sans sqrt
            float wgt = kernelD * kE;
            norm += wgt;
            acc0 += wgt * s0;
            acc1 += wgt * s1;
            acc2 += wgt * s2;
        }
    }

    float inv_norm = 1.0f / norm;
    size_t ob = (size_t)b * 3 * HW;
    out[ob + p] = acc0 * inv_norm;
    out[ob + HW + p] = acc1 * inv_norm;
    out[ob + 2 * HW + p] = acc2 * inv_norm;
}

// ---------------- fallback (round-1 scalar kernel, used if ws too small) ----
__global__ __launch_bounds__(256) void fab_kernel(
    const float* __restrict__ x,
    const float* __restrict__ tangent,
    const float* __restrict__ sigmaD,
    const float* __restrict__ sigmaR,
    float* __restrict__ out,
    int npix)
{
    int idx = blockIdx.x * blockDim.x + threadIdx.x;
    if (idx >= npix) return;
    int b = idx / HW;
    int p = idx - b * HW;
    int h = p / WW;
    int w = p - h * WW;

    const float* xb = x + (size_t)b * 3 * HW;

    float tx = tangent[(size_t)b * 2 * HW + p];
    float ty = tangent[(size_t)b * 2 * HW + HW + p];
    float me = fmaxf(fabsf(tx), fabsf(ty));
    float ds = (me > 0.0f) ? (1.0f / me) : 1.0f;

    float sD = sigmaD[b];
    float sR = sigmaR[b];
    float half_step = 2.0f * sD;
    float nD = -1.0f / (2.0f * sD * sD + F_EPS);
    float nR = -1.0f / (2.0f * sR * sR + F_EPS);

    float c0c = xb[p];
    float c1c = xb[HW + p];
    float c2c = xb[2 * HW + p];
    float acc0 = c0c, acc1 = c1c, acc2 = c2c;
    float norm = 1.0f;

#pragma unroll
    for (int t = 0; t < NTAPS; ++t) {
        float it1 = (float)(2 * t + 1);
        float it2 = (float)(2 * t + 2);
        float itr1 = ds * it1;
        float itr2 = ds * it2;
        if (fabsf(itr1) > half_step) continue;
        float kD1 = __expf(itr1 * itr1 * nD);
        float kD2 = __expf(itr2 * itr2 * nD);
        float kernelD = kD1 + kD2;
        float itr_d = (itr1 * kD1 + itr2 * kD2) / (kernelD + F_EPS);
        float ox = itr_d * tx;
        float oy = itr_d * ty;

#pragma unroll
        for (int s = 0; s < 2; ++s) {
            float xpf = (s == 0) ? ((float)w + ox) : ((float)w - ox);
            float ypf = (s == 0) ? ((float)h + oy) : ((float)h - oy);
            float x0f = floorf(xpf);
            float y0f = floorf(ypf);
            float fx = xpf - x0f;
            float fy = ypf - y0f;
            int x0i = min(max((int)x0f, 0), WW - 1);
            int x1i = min(max((int)x0f + 1, 0), WW - 1);
            int y0i = min(max((int)y0f, 0), HH - 1);
            int y1i = min(max((int)y0f + 1, 0), HH - 1);
            int i00 = y0i * WW + x0i;
            int i01 = y0i * WW + x1i;
            int i10 = y1i * WW + x0i;
            int i11 = y1i * WW + x1i;

            float gx = 1.0f - fx, gy = 1.0f - fy;
            float s0 = (xb[i00] * gx + xb[i01] * fx) * gy + (xb[i10] * gx + xb[i11] * fx) * fy;
            float s1 = (xb[HW + i00] * gx + xb[HW + i01] * fx) * gy + (xb[HW + i10] * gx + xb[HW + i11] * fx) * fy;
            float s2 = (xb[2 * HW + i00] * gx + xb[2 * HW + i01] * fx) * gy + (xb[2 * HW + i10] * gx + xb[2 * HW + i11] * fx) * fy;

            float cc0 = (s0 - c0c) * 100.0f;
            float cc1 = (s1 - c1c) * 254.0f;
            float cc2 = (s2 - c2c) * 254.0f;
            float e2 = fmaxf(cc0 * cc0 + cc1 * cc1 + cc2 * cc2, 1e-30f);
            float kE = __expf(e2 * nR);
            float wgt = kernelD * kE;
            norm += wgt;
            acc0 += wgt * s0;
            acc1 += wgt * s1;
            acc2 += wgt * s2;
        }
    }

    float inv_norm = 1.0f / norm;
    size_t ob = (size_t)b * 3 * HW;
    out[ob + p] = acc0 * inv_norm;
    out[ob + HW + p] = acc1 * inv_norm;
    out[ob + 2 * HW + p] = acc2 * inv_norm;
}

extern "C" void kernel_launch(void* const* d_in, const int* in_sizes, int n_in,
                              void* d_out, int out_size, void* d_ws, size_t ws_size,
                              hipStream_t stream) {
    const float* x = (const float*)d_in[0];
    const float* tangent = (const float*)d_in[1];
    const float* sigmaD = (const float*)d_in[2];
    const float* sigmaR = (const float*)d_in[3];
    float* out = (float*)d_out;

    int bs = in_sizes[2];           // sigmaD has one entry per batch
    int npix = bs * HW;
    int block = 256;
    int grid = (npix + block - 1) / block;

    size_t need = (size_t)npix * sizeof(float4);
    if (ws_size >= need) {
        float4* xp4 = (float4*)d_ws;
        pack_kernel<<<grid, block, 0, stream>>>(x, xp4, npix);
        fab_kernel4<<<grid, block, 0, stream>>>(xp4, tangent, sigmaD, sigmaR, out, npix);
    } else {
        fab_kernel<<<grid, block, 0, stream>>>(x, tangent, sigmaD, sigmaR, out, npix);
    }
}

// Round 3
// 52.874 us; speedup vs baseline: 2.9629x; 1.6132x over previous
//
#include <hip/hip_runtime.h>
#include <math.h>

#define HH 768
#define WW 1024
#define HW (HH * WW)
#define NTAPS 5
#define F_EPS 1.1920929e-07f

#define TS  32          // tile size (pixels)
#define RAD 12          // halo radius (max sample offset is <11 px)
#define TW  (TS + 2*RAD)   // 56: halo window extent
#define TP  57             // padded LDS row stride (float4 units)

// ---------------- pack kernel: planar RGB -> float4 ----------------
__global__ __launch_bounds__(256) void pack_kernel(
    const float* __restrict__ x, float4* __restrict__ xp, int npix)
{
    int i = blockIdx.x * blockDim.x + threadIdx.x;
    if (i >= npix) return;
    int b = i / HW;
    int p = i - b * HW;
    const float* xb = x + (size_t)b * 3 * HW;
    float4 v;
    v.x = xb[p];
    v.y = xb[HW + p];
    v.z = xb[2 * HW + p];
    v.w = 0.0f;
    xp[i] = v;
}

// ---------------- per-pixel tap loop (templated on border handling) --------
template<bool BORDER>
__device__ __forceinline__ void fab_process(
    const float4* __restrict__ tile,
    float ds, float tx, float ty, float sD, float nD, float nR,
    float wf, float hf, int bx, int by,
    float4 c, float& norm, float& acc0, float& acc1, float& acc2)
{
    float half_step = 2.0f * sD;
    // Gaussian recurrence: kD(n) = exp(nD*(ds*n)^2) = Q^(n^2), Q = exp(nD*ds*ds)
    float Q  = __expf(ds * ds * nD);
    float Q2 = Q * Q;
    float pw = Q;        // Q^(n^2), n = 1
    float rq = Q2 * Q;   // Q^(2n+1), n = 1
#pragma unroll
    for (int t = 0; t < NTAPS; ++t) {
        float it1 = (float)(2 * t + 1);
        float it2 = (float)(2 * t + 2);
        float itr1 = ds * it1;
        float itr2 = ds * it2;
        float kD1 = pw; pw *= rq; rq *= Q2;
        float kD2 = pw; pw *= rq; rq *= Q2;
        // kernelD == 0 exactly when itr1 > half_step (ds>0) -> contribution 0
        if (itr1 > half_step) continue;
        float kernelD = kD1 + kD2;
        float itr_d = (itr1 * kD1 + itr2 * kD2) / (kernelD + F_EPS);
        float ox = itr_d * tx;
        float oy = itr_d * ty;
#pragma unroll
        for (int s = 0; s < 2; ++s) {
            float xpf = (s == 0) ? (wf + ox) : (wf - ox);
            float ypf = (s == 0) ? (hf + oy) : (hf - oy);
            float x0f = floorf(xpf);
            float y0f = floorf(ypf);
            float fx = xpf - x0f;
            float fy = ypf - y0f;
            float4 q00, q01, q10, q11;
            if (BORDER) {
                int x0r = (int)x0f, y0r = (int)y0f;
                int x0i = min(max(x0r, 0), WW - 1);
                int x1i = min(max(x0r + 1, 0), WW - 1);
                int y0i = min(max(y0r, 0), HH - 1);
                int y1i = min(max(y0r + 1, 0), HH - 1);
                int j0 = x0i + bx, j1 = x1i + bx;
                int i0 = y0i + by, i1 = y1i + by;
                q00 = tile[i0 * TP + j0];
                q01 = tile[i0 * TP + j1];
                q10 = tile[i1 * TP + j0];
                q11 = tile[i1 * TP + j1];
            } else {
                int j0 = (int)x0f + bx;
                int i0 = (int)y0f + by;
                const float4* cell = tile + (i0 * TP + j0);
                q00 = cell[0];
                q01 = cell[1];
                q10 = cell[TP];
                q11 = cell[TP + 1];
            }
            float gx = 1.0f - fx, gy = 1.0f - fy;
            float w00 = gx * gy, w01 = fx * gy, w10 = gx * fy, w11 = fx * fy;
            float s0 = w00 * q00.x + w01 * q01.x + w10 * q10.x + w11 * q11.x;
            float s1 = w00 * q00.y + w01 * q01.y + w10 * q10.y + w11 * q11.y;
            float s2 = w00 * q00.z + w01 * q01.z + w10 * q10.z + w11 * q11.z;
            float cc0 = (s0 - c.x) * 100.0f;
            float cc1 = (s1 - c.y) * 254.0f;
            float cc2 = (s2 - c.z) * 254.0f;
            float e2 = fmaxf(cc0 * cc0 + cc1 * cc1 + cc2 * cc2, 1e-30f);
            float kE = __expf(e2 * nR);
            float wgt = kernelD * kE;
            norm += wgt;
            acc0 += wgt * s0;
            acc1 += wgt * s1;
            acc2 += wgt * s2;
        }
    }
}

// ---------------- tiled main kernel ----------------
__global__ __launch_bounds__(1024, 8) void fab_tile(
    const float4* __restrict__ xp4,
    const float* __restrict__ tangent,
    const float* __restrict__ sigmaD,
    const float* __restrict__ sigmaR,
    float* __restrict__ out)
{
    __shared__ float4 tile[TW * TP];
    const int tiles_x = WW / TS;           // 32
    const int tiles_y = HH / TS;           // 24
    const int tpb = tiles_x * tiles_y;     // 768
    int tid = threadIdx.x;
    int bid = blockIdx.x;
    int b = bid / tpb;
    int tq = bid - b * tpb;
    int tyi = tq / tiles_x;
    int txi = tq - tyi * tiles_x;
    int tx0 = txi * TS, ty0 = tyi * TS;

    const float4* xb = xp4 + (size_t)b * HW;

    // stage halo window into LDS (border-clamped)
    for (int cI = tid; cI < TW * TW; cI += 1024) {
        int lyy = cI / TW;
        int lxx = cI - lyy * TW;
        int gx = min(max(tx0 - RAD + lxx, 0), WW - 1);
        int gy = min(max(ty0 - RAD + lyy, 0), HH - 1);
        tile[lyy * TP + lxx] = xb[gy * WW + gx];
    }
    __syncthreads();

    int lx = tid & (TS - 1);
    int ly = tid >> 5;
    int w = tx0 + lx, h = ty0 + ly;
    int p = h * WW + w;

    float tx = tangent[(size_t)b * 2 * HW + p];
    float ty = tangent[(size_t)b * 2 * HW + HW + p];
    float me = fmaxf(fabsf(tx), fabsf(ty));
    float ds = (me > 0.0f) ? (1.0f / me) : 1.0f;
    float sD = sigmaD[b], sR = sigmaR[b];
    float nD = -1.0f / (2.0f * sD * sD + F_EPS);
    float nR = -1.0f / (2.0f * sR * sR + F_EPS);

    float4 c = tile[(ly + RAD) * TP + (lx + RAD)];
    float norm = 1.0f, acc0 = c.x, acc1 = c.y, acc2 = c.z;
    int bx = RAD - tx0, by = RAD - ty0;

    bool interior = (tx0 >= RAD) && (tx0 + TS + RAD <= WW) &&
                    (ty0 >= RAD) && (ty0 + TS + RAD <= HH);
    if (interior)
        fab_process<false>(tile, ds, tx, ty, sD, nD, nR,
                           (float)w, (float)h, bx, by, c, norm, acc0, acc1, acc2);
    else
        fab_process<true>(tile, ds, tx, ty, sD, nD, nR,
                          (float)w, (float)h, bx, by, c, norm, acc0, acc1, acc2);

    float inv = 1.0f / norm;
    size_t ob = (size_t)b * 3 * HW;
    out[ob + p] = acc0 * inv;
    out[ob + HW + p] = acc1 * inv;
    out[ob + 2 * HW + p] = acc2 * inv;
}

// ---------------- fallback (round-1 style planar kernel, no workspace) -----
__global__ __launch_bounds__(256) void fab_kernel(
    const float* __restrict__ x,
    const float* __restrict__ tangent,
    const float* __restrict__ sigmaD,
    const float* __restrict__ sigmaR,
    float* __restrict__ out,
    int npix)
{
    int idx = blockIdx.x * blockDim.x + threadIdx.x;
    if (idx >= npix) return;
    int b = idx / HW;
    int p = idx - b * HW;
    int h = p / WW;
    int w = p - h * WW;

    const float* xb = x + (size_t)b * 3 * HW;

    float tx = tangent[(size_t)b * 2 * HW + p];
    float ty = tangent[(size_t)b * 2 * HW + HW + p];
    float me = fmaxf(fabsf(tx), fabsf(ty));
    float ds = (me > 0.0f) ? (1.0f / me) : 1.0f;
    float sD = sigmaD[b], sR = sigmaR[b];
    float half_step = 2.0f * sD;
    float nD = -1.0f / (2.0f * sD * sD + F_EPS);
    float nR = -1.0f / (2.0f * sR * sR + F_EPS);

    float c0c = xb[p], c1c = xb[HW + p], c2c = xb[2 * HW + p];
    float acc0 = c0c, acc1 = c1c, acc2 = c2c;
    float norm = 1.0f;

#pragma unroll
    for (int t = 0; t < NTAPS; ++t) {
        float it1 = (float)(2 * t + 1);
        float it2 = (float)(2 * t + 2);
        float itr1 = ds * it1;
        float itr2 = ds * it2;
        if (fabsf(itr1) > half_step) continue;
        float kD1 = __expf(itr1 * itr1 * nD);
        float kD2 = __expf(itr2 * itr2 * nD);
        float kernelD = kD1 + kD2;
        float itr_d = (itr1 * kD1 + itr2 * kD2) / (kernelD + F_EPS);
        float ox = itr_d * tx;
        float oy = itr_d * ty;
#pragma unroll
        for (int s = 0; s < 2; ++s) {
            float xpf = (s == 0) ? ((float)w + ox) : ((float)w - ox);
            float ypf = (s == 0) ? ((float)h + oy) : ((float)h - oy);
            float x0f = floorf(xpf);
            float y0f = floorf(ypf);
            float fx = xpf - x0f, fy = ypf - y0f;
            int x0i = min(max((int)x0f, 0), WW - 1);
            int x1i = min(max((int)x0f + 1, 0), WW - 1);
            int y0i = min(max((int)y0f, 0), HH - 1);
            int y1i = min(max((int)y0f + 1, 0), HH - 1);
            int i00 = y0i * WW + x0i, i01 = y0i * WW + x1i;
            int i10 = y1i * WW + x0i, i11 = y1i * WW + x1i;
            float gx = 1.0f - fx, gy = 1.0f - fy;
            float s0 = (xb[i00] * gx + xb[i01] * fx) * gy + (xb[i10] * gx + xb[i11] * fx) * fy;
            float s1 = (xb[HW + i00] * gx + xb[HW + i01] * fx) * gy + (xb[HW + i10] * gx + xb[HW + i11] * fx) * fy;
            float s2 = (xb[2 * HW + i00] * gx + xb[2 * HW + i01] * fx) * gy + (xb[2 * HW + i10] * gx + xb[2 * HW + i11] * fx) * fy;
            float cc0 = (s0 - c0c) * 100.0f;
            float cc1 = (s1 - c1c) * 254.0f;
            float cc2 = (s2 - c2c) * 254.0f;
            float e2 = fmaxf(cc0 * cc0 + cc1 * cc1 + cc2 * cc2, 1e-30f);
            float kE = __expf(e2 * nR);
            float wgt = kernelD * kE;
            norm += wgt;
            acc0 += wgt * s0;
            acc1 += wgt * s1;
            acc2 += wgt * s2;
        }
    }

    float inv = 1.0f / norm;
    size_t ob = (size_t)b * 3 * HW;
    out[ob + p] = acc0 * inv;
    out[ob + HW + p] = acc1 * inv;
    out[ob + 2 * HW + p] = acc2 * inv;
}

extern "C" void kernel_launch(void* const* d_in, const int* in_sizes, int n_in,
                              void* d_out, int out_size, void* d_ws, size_t ws_size,
                              hipStream_t stream) {
    const float* x = (const float*)d_in[0];
    const float* tangent = (const float*)d_in[1];
    const float* sigmaD = (const float*)d_in[2];
    const float* sigmaR = (const float*)d_in[3];
    float* out = (float*)d_out;

    int bs = in_sizes[2];           // sigmaD has one entry per batch
    int npix = bs * HW;

    size_t need = (size_t)npix * sizeof(float4);
    if (ws_size >= need) {
        float4* xp4 = (float4*)d_ws;
        int block = 256;
        int grid = (npix + block - 1) / block;
        pack_kernel<<<grid, block, 0, stream>>>(x, xp4, npix);
        int tpb = (WW / TS) * (HH / TS);
        fab_tile<<<bs * tpb, 1024, 0, stream>>>(xp4, tangent, sigmaD, sigmaR, out);
    } else {
        int block = 256;
        int grid = (npix + block - 1) / block;
        fab_kernel<<<grid, block, 0, stream>>>(x, tangent, sigmaD, sigmaR, out, npix);
    }
}

// Round 4
// 48.364 us; speedup vs baseline: 3.2392x; 1.0932x over previous
//
#include <hip/hip_runtime.h>
#include <hip/hip_fp16.h>
#include <math.h>

#define HH 768
#define WW 1024
#define HW (HH * WW)
#define NTAPS 5
#define F_EPS 1.1920929e-07f

#define TS  32             // tile size (pixels)
#define RAD 12             // halo radius (max |pixel offset| <= 10, +1 corner, +1 slack)
#define TW  (TS + 2*RAD)   // 56
#define TP  57             // padded LDS row stride (texels)

union HU { __half2 h2; unsigned u; };

// ---- pack kernel: planar RGB -> {f32 100*c0, half2(254*c1, 254*c2)} ------
__global__ __launch_bounds__(256) void pack_kernel(
    const float* __restrict__ x, uint2* __restrict__ xp, int npix)
{
    int i = blockIdx.x * blockDim.x + threadIdx.x;
    if (i >= npix) return;
    int b = i / HW;
    int p = i - b * HW;
    const float* xb = x + (size_t)b * 3 * HW;
    float a = xb[p] * 100.0f;
    float c1 = xb[HW + p] * 254.0f;
    float c2 = xb[2 * HW + p] * 254.0f;
    HU cv; cv.h2 = __floats2half2_rn(c1, c2);
    uint2 v;
    v.x = __float_as_uint(a);
    v.y = cv.u;
    xp[i] = v;
}

// ---- tiled main kernel ----------------------------------------------------
__global__ __launch_bounds__(1024, 2) void fab_tile(
    const uint2* __restrict__ xp8,
    const float* __restrict__ x,
    const float* __restrict__ tangent,
    const float* __restrict__ sigmaD,
    const float* __restrict__ sigmaR,
    float* __restrict__ out)
{
    __shared__ uint2 tile[TW * TP];
    const int tiles_x = WW / TS;           // 32
    const int tiles_y = HH / TS;           // 24
    const int tpb = tiles_x * tiles_y;     // 768
    int tid = threadIdx.x;
    int bid = blockIdx.x;
    int b = bid / tpb;
    int tq = bid - b * tpb;
    int tyi = tq / tiles_x;
    int txi = tq - tyi * tiles_x;
    int tx0 = txi * TS, ty0 = tyi * TS;

    const uint2* xb8 = xp8 + (size_t)b * HW;

    // stage halo window into LDS (border-clamped -> border replication makes
    // all per-sample clamping unnecessary)
    for (int cI = tid; cI < TW * TW; cI += 1024) {
        int syy = cI / TW;
        int sxx = cI - syy * TW;
        int sgx = min(max(tx0 - RAD + sxx, 0), WW - 1);
        int sgy = min(max(ty0 - RAD + syy, 0), HH - 1);
        tile[syy * TP + sxx] = xb8[sgy * WW + sgx];
    }
    __syncthreads();

    int lx = tid & (TS - 1);
    int ly = tid >> 5;
    int w = tx0 + lx, h = ty0 + ly;
    int p = h * WW + w;

    float tx = tangent[(size_t)b * 2 * HW + p];
    float ty = tangent[(size_t)b * 2 * HW + HW + p];
    float me = fmaxf(fabsf(tx), fabsf(ty));
    float ds = (me > 0.0f) ? (1.0f / me) : 1.0f;
    float sD = sigmaD[b], sR = sigmaR[b];
    float half_step = 2.0f * sD;
    float nD = -1.0f / (2.0f * sD * sD + F_EPS);
    float nR = -1.0f / (2.0f * sR * sR + F_EPS);

    // exact (pre-scaled) center values
    const float* xb = x + (size_t)b * 3 * HW;
    uint2 ctex = tile[(ly + RAD) * TP + (lx + RAD)];
    float C0 = __uint_as_float(ctex.x);            // exact 100*c0
    float C1 = xb[HW + p] * 254.0f;                // exact 254*c1
    float C2 = xb[2 * HW + p] * 254.0f;            // exact 254*c2

    float norm = 1.0f;
    float a0 = C0, a1 = C1, a2 = C2;
    int bx = RAD - tx0, by = RAD - ty0;
    float wf = (float)w, hf = (float)h;

    // Gaussian recurrence: kD(n) = Q^(n^2), Q = exp(nD*ds*ds)
    float Q  = __expf(ds * ds * nD);
    float Q2 = Q * Q;
    float pw = Q;        // Q^(n^2), n=1
    float rq = Q2 * Q;   // Q^(2n+1), n=1

#pragma unroll
    for (int t = 0; t < NTAPS; ++t) {
        float itr1 = ds * (float)(2 * t + 1);
        float itr2 = ds * (float)(2 * t + 2);
        float kD1 = pw; pw *= rq; rq *= Q2;
        float kD2 = pw; pw *= rq; rq *= Q2;
        if (itr1 > half_step) continue;   // kernelD == 0 exactly -> no contribution
        float kernelD = kD1 + kD2;
        float itr_d = (itr1 * kD1 + itr2 * kD2) / (kernelD + F_EPS);
        float ox = itr_d * tx;
        float oy = itr_d * ty;
#pragma unroll
        for (int s = 0; s < 2; ++s) {
            float xpf = s ? (wf - ox) : (wf + ox);
            float ypf = s ? (hf - oy) : (hf + oy);
            float x0f = floorf(xpf);
            float y0f = floorf(ypf);
            float fx = xpf - x0f;
            float fy = ypf - y0f;
            int j0 = (int)x0f + bx;
            int i0 = (int)y0f + by;
            const uint2* cell = tile + (i0 * TP + j0);
            uint2 r00 = cell[0];
            uint2 r01 = cell[1];
            uint2 r10 = cell[TP];
            uint2 r11 = cell[TP + 1];

            float gx = 1.0f - fx, gy = 1.0f - fy;
            float w00 = gx * gy, w01 = fx * gy, w10 = gx * fy, w11 = fx * fy;

            float s0 = w00 * __uint_as_float(r00.x) + w01 * __uint_as_float(r01.x)
                     + w10 * __uint_as_float(r10.x) + w11 * __uint_as_float(r11.x);
            HU u00, u01, u10, u11;
            u00.u = r00.y; u01.u = r01.y; u10.u = r10.y; u11.u = r11.y;
            float2 f00 = __half22float2(u00.h2);
            float2 f01 = __half22float2(u01.h2);
            float2 f10 = __half22float2(u10.h2);
            float2 f11 = __half22float2(u11.h2);
            float s1 = w00 * f00.x + w01 * f01.x + w10 * f10.x + w11 * f11.x;
            float s2 = w00 * f00.y + w01 * f01.y + w10 * f10.y + w11 * f11.y;

            float cc0 = s0 - C0;
            float cc1 = s1 - C1;
            float cc2 = s2 - C2;
            float e2 = fmaxf(cc0 * cc0 + cc1 * cc1 + cc2 * cc2, 1e-30f);
            float kE = __expf(e2 * nR);
            float wgt = kernelD * kE;
            norm += wgt;
            a0 += wgt * s0;
            a1 += wgt * s1;
            a2 += wgt * s2;
        }
    }

    float inv = 1.0f / norm;
    size_t ob = (size_t)b * 3 * HW;
    out[ob + p]          = a0 * inv * 0.01f;
    out[ob + HW + p]     = a1 * inv * (1.0f / 254.0f);
    out[ob + 2 * HW + p] = a2 * inv * (1.0f / 254.0f);
}

// ---- fallback (round-2 planar kernel, used only if ws too small) ----------
__global__ __launch_bounds__(256) void fab_kernel(
    const float* __restrict__ x,
    const float* __restrict__ tangent,
    const float* __restrict__ sigmaD,
    const float* __restrict__ sigmaR,
    float* __restrict__ out,
    int npix)
{
    int idx = blockIdx.x * blockDim.x + threadIdx.x;
    if (idx >= npix) return;
    int b = idx / HW;
    int p = idx - b * HW;
    int h = p / WW;
    int w = p - h * WW;

    const float* xb = x + (size_t)b * 3 * HW;
    float tx = tangent[(size_t)b * 2 * HW + p];
    float ty = tangent[(size_t)b * 2 * HW + HW + p];
    float me = fmaxf(fabsf(tx), fabsf(ty));
    float ds = (me > 0.0f) ? (1.0f / me) : 1.0f;
    float sD = sigmaD[b], sR = sigmaR[b];
    float half_step = 2.0f * sD;
    float nD = -1.0f / (2.0f * sD * sD + F_EPS);
    float nR = -1.0f / (2.0f * sR * sR + F_EPS);

    float c0c = xb[p], c1c = xb[HW + p], c2c = xb[2 * HW + p];
    float acc0 = c0c, acc1 = c1c, acc2 = c2c;
    float norm = 1.0f;

#pragma unroll
    for (int t = 0; t < NTAPS; ++t) {
        float itr1 = ds * (float)(2 * t + 1);
        float itr2 = ds * (float)(2 * t + 2);
        if (itr1 > half_step) continue;
        float kD1 = __expf(itr1 * itr1 * nD);
        float kD2 = __expf(itr2 * itr2 * nD);
        float kernelD = kD1 + kD2;
        float itr_d = (itr1 * kD1 + itr2 * kD2) / (kernelD + F_EPS);
        float ox = itr_d * tx;
        float oy = itr_d * ty;
#pragma unroll
        for (int s = 0; s < 2; ++s) {
            float xpf = s ? ((float)w - ox) : ((float)w + ox);
            float ypf = s ? ((float)h - oy) : ((float)h + oy);
            float x0f = floorf(xpf);
            float y0f = floorf(ypf);
            float fx = xpf - x0f, fy = ypf - y0f;
            int x0i = min(max((int)x0f, 0), WW - 1);
            int x1i = min(max((int)x0f + 1, 0), WW - 1);
            int y0i = min(max((int)y0f, 0), HH - 1);
            int y1i = min(max((int)y0f + 1, 0), HH - 1);
            int i00 = y0i * WW + x0i, i01 = y0i * WW + x1i;
            int i10 = y1i * WW + x0i, i11 = y1i * WW + x1i;
            float gx = 1.0f - fx, gy = 1.0f - fy;
            float s0 = (xb[i00] * gx + xb[i01] * fx) * gy + (xb[i10] * gx + xb[i11] * fx) * fy;
            float s1 = (xb[HW + i00] * gx + xb[HW + i01] * fx) * gy + (xb[HW + i10] * gx + xb[HW + i11] * fx) * fy;
            float s2 = (xb[2 * HW + i00] * gx + xb[2 * HW + i01] * fx) * gy + (xb[2 * HW + i10] * gx + xb[2 * HW + i11] * fx) * fy;
            float cc0 = (s0 - c0c) * 100.0f;
            float cc1 = (s1 - c1c) * 254.0f;
            float cc2 = (s2 - c2c) * 254.0f;
            float e2 = fmaxf(cc0 * cc0 + cc1 * cc1 + cc2 * cc2, 1e-30f);
            float kE = __expf(e2 * nR);
            float wgt = kernelD * kE;
            norm += wgt;
            acc0 += wgt * s0;
            acc1 += wgt * s1;
            acc2 += wgt * s2;
        }
    }

    float inv = 1.0f / norm;
    size_t ob = (size_t)b * 3 * HW;
    out[ob + p] = acc0 * inv;
    out[ob + HW + p] = acc1 * inv;
    out[ob + 2 * HW + p] = acc2 * inv;
}

extern "C" void kernel_launch(void* const* d_in, const int* in_sizes, int n_in,
                              void* d_out, int out_size, void* d_ws, size_t ws_size,
                              hipStream_t stream) {
    const float* x = (const float*)d_in[0];
    const float* tangent = (const float*)d_in[1];
    const float* sigmaD = (const float*)d_in[2];
    const float* sigmaR = (const float*)d_in[3];
    float* out = (float*)d_out;

    int bs = in_sizes[2];           // sigmaD has one entry per batch
    int npix = bs * HW;

    size_t need = (size_t)npix * sizeof(uint2);
    if (ws_size >= need) {
        uint2* xp8 = (uint2*)d_ws;
        int block = 256;
        int grid = (npix + block - 1) / block;
        pack_kernel<<<grid, block, 0, stream>>>(x, xp8, npix);
        int tpb = (WW / TS) * (HH / TS);
        fab_tile<<<bs * tpb, 1024, 0, stream>>>(xp8, x, tangent, sigmaD, sigmaR, out);
    } else {
        int block = 256;
        int grid = (npix + block - 1) / block;
        fab_kernel<<<grid, block, 0, stream>>>(x, tangent, sigmaD, sigmaR, out, npix);
    }
}

// Round 6
// 41.151 us; speedup vs baseline: 3.8070x; 1.1753x over previous
//
#include <hip/hip_runtime.h>
#include <hip/hip_fp16.h>
#include <math.h>

#define HH 768
#define WW 1024
#define HW (HH * WW)
#define NTAPS 5
#define F_EPS 1.1920929e-07f

#define TS  32             // tile size (pixels)
#define RAD 12             // halo radius (max |pixel offset| <= 10, +1 corner, +1 slack)
#define TW  (TS + 2*RAD)   // 56
#define TP  57             // padded LDS row stride (texels)

typedef __fp16 h2 __attribute__((ext_vector_type(2)));
union H2U { h2 h; unsigned u; };

__device__ __forceinline__ float fast_rcp(float v) {
    return __builtin_amdgcn_rcpf(v);
}

// ---- fused tiled kernel (stages + scales + packs inline, no workspace) ----
__global__ __launch_bounds__(1024, 2) void fab_tile(
    const float* __restrict__ x,
    const float* __restrict__ tangent,
    const float* __restrict__ sigmaD,
    const float* __restrict__ sigmaR,
    float* __restrict__ out)
{
    __shared__ uint2 tile[TW * TP];
    const int tiles_x = WW / TS;           // 32
    const int tiles_y = HH / TS;           // 24
    const int tpb = tiles_x * tiles_y;     // 768
    int tid = threadIdx.x;
    int bid = blockIdx.x;
    int b = bid / tpb;
    int tq = bid - b * tpb;
    int tyi = tq / tiles_x;
    int txi = tq - tyi * tiles_x;
    int tx0 = txi * TS, ty0 = tyi * TS;

    const float* xb = x + (size_t)b * 3 * HW;

    // stage halo window into LDS, scaling + packing inline.
    // Border-clamped staging -> border replication makes per-sample clamping
    // unnecessary (|sample displacement| <= 10 < RAD).
    for (int cI = tid; cI < TW * TW; cI += 1024) {
        int syy = cI / TW;
        int sxx = cI - syy * TW;
        int sgx = min(max(tx0 - RAD + sxx, 0), WW - 1);
        int sgy = min(max(ty0 - RAD + syy, 0), HH - 1);
        int g = sgy * WW + sgx;
        float a  = xb[g] * 100.0f;
        float c1 = xb[HW + g] * 254.0f;
        float c2 = xb[2 * HW + g] * 254.0f;
        H2U cv; cv.h = __builtin_amdgcn_cvt_pkrtz(c1, c2);
        uint2 v;
        v.x = __float_as_uint(a);
        v.y = cv.u;
        tile[syy * TP + sxx] = v;
    }
    __syncthreads();

    int lx = tid & (TS - 1);
    int ly = tid >> 5;
    int w = tx0 + lx, h = ty0 + ly;
    int p = h * WW + w;

    float tx = tangent[(size_t)b * 2 * HW + p];
    float ty = tangent[(size_t)b * 2 * HW + HW + p];
    float me = fmaxf(fabsf(tx), fabsf(ty));
    float ds = (me > 0.0f) ? fast_rcp(me) : 1.0f;
    float sD = sigmaD[b], sR = sigmaR[b];
    float half_step = 2.0f * sD;
    float nD = -fast_rcp(2.0f * sD * sD + F_EPS);
    float nR = -fast_rcp(2.0f * sR * sR + F_EPS);

    // exact (pre-scaled) center values
    uint2 ctex = tile[(ly + RAD) * TP + (lx + RAD)];
    float C0 = __uint_as_float(ctex.x);            // exact 100*c0
    float C1 = xb[HW + p] * 254.0f;                // exact 254*c1
    float C2 = xb[2 * HW + p] * 254.0f;            // exact 254*c2

    float norm = 1.0f;
    float a0 = C0, a1 = C1, a2 = C2;
    int bx = RAD - tx0, by = RAD - ty0;
    float wf = (float)w, hf = (float)h;

    // Gaussian recurrence: kD(n) = Q^(n^2), Q = exp(nD*ds*ds)
    float Q  = __expf(ds * ds * nD);
    float Q2 = Q * Q;
    float pw = Q;        // Q^(n^2), n=1
    float rq = Q2 * Q;   // Q^(2n+1), n=1

#pragma unroll
    for (int t = 0; t < NTAPS; ++t) {
        float itr1 = ds * (float)(2 * t + 1);
        float itr2 = ds * (float)(2 * t + 2);
        float kD1 = pw; pw *= rq; rq *= Q2;
        float kD2 = pw; pw *= rq; rq *= Q2;
        if (itr1 > half_step) continue;   // kernelD == 0 exactly -> no contribution
        float kernelD = kD1 + kD2;
        float itr_d = (itr1 * kD1 + itr2 * kD2) * fast_rcp(kernelD + F_EPS);
        float ox = itr_d * tx;
        float oy = itr_d * ty;
#pragma unroll
        for (int s = 0; s < 2; ++s) {
            float xpf = s ? (wf - ox) : (wf + ox);
            float ypf = s ? (hf - oy) : (hf + oy);
            float x0f = floorf(xpf);
            float y0f = floorf(ypf);
            float fx = xpf - x0f;
            float fy = ypf - y0f;
            int j0 = (int)x0f + bx;
            int i0 = (int)y0f + by;
            const uint2* cell = tile + (i0 * TP + j0);
            uint2 r00 = cell[0];
            uint2 r01 = cell[1];
            uint2 r10 = cell[TP];
            uint2 r11 = cell[TP + 1];

            float gx = 1.0f - fx, gy = 1.0f - fy;
            float w00 = gx * gy, w01 = fx * gy, w10 = gx * fy, w11 = fx * fy;

            // channel 0 in f32
            float s0 = w00 * __uint_as_float(r00.x) + w01 * __uint_as_float(r01.x)
                     + w10 * __uint_as_float(r10.x) + w11 * __uint_as_float(r11.x);

            // channels 1,2 in packed fp16 (texels already v2f16 in registers)
            H2U u00, u01, u10, u11;
            u00.u = r00.y; u01.u = r01.y; u10.u = r10.y; u11.u = r11.y;
            h2 W00 = __builtin_amdgcn_cvt_pkrtz(w00, w00);
            h2 W01 = __builtin_amdgcn_cvt_pkrtz(w01, w01);
            h2 W10 = __builtin_amdgcn_cvt_pkrtz(w10, w10);
            h2 W11 = __builtin_amdgcn_cvt_pkrtz(w11, w11);
            h2 s12 = W00 * u00.h + W01 * u01.h + W10 * u10.h + W11 * u11.h;
            float s1 = (float)s12.x;
            float s2 = (float)s12.y;

            float cc0 = s0 - C0;
            float cc1 = s1 - C1;
            float cc2 = s2 - C2;
            float e2 = fmaxf(cc0 * cc0 + cc1 * cc1 + cc2 * cc2, 1e-30f);
            float kE = __expf(e2 * nR);
            float wgt = kernelD * kE;
            norm += wgt;
            a0 += wgt * s0;
            a1 += wgt * s1;
            a2 += wgt * s2;
        }
    }

    float inv = fast_rcp(norm);
    size_t ob = (size_t)b * 3 * HW;
    out[ob + p]          = a0 * inv * 0.01f;
    out[ob + HW + p]     = a1 * inv * (1.0f / 254.0f);
    out[ob + 2 * HW + p] = a2 * inv * (1.0f / 254.0f);
}

extern "C" void kernel_launch(void* const* d_in, const int* in_sizes, int n_in,
                              void* d_out, int out_size, void* d_ws, size_t ws_size,
                              hipStream_t stream) {
    const float* x = (const float*)d_in[0];
    const float* tangent = (const float*)d_in[1];
    const float* sigmaD = (const float*)d_in[2];
    const float* sigmaR = (const float*)d_in[3];
    float* out = (float*)d_out;

    int bs = in_sizes[2];           // sigmaD has one entry per batch
    int tpb = (WW / TS) * (HH / TS);
    fab_tile<<<bs * tpb, 1024, 0, stream>>>(x, tangent, sigmaD, sigmaR, out);
}

// Round 7
// 41.038 us; speedup vs baseline: 3.8175x; 1.0028x over previous
//
#include <hip/hip_runtime.h>
#include <hip/hip_fp16.h>
#include <math.h>

#define HH 768
#define WW 1024
#define HW (HH * WW)
#define NTAPS 5
#define F_EPS 1.1920929e-07f

#define TS  32             // tile size (pixels)
#define RAD 11             // halo radius (max |pixel offset| <= 10, +1 for x0+1 corner)
#define TW  (TS + 2*RAD)   // 54
#define TP  55             // padded LDS row stride (texels)

typedef __fp16 h2 __attribute__((ext_vector_type(2)));
typedef float  f2 __attribute__((ext_vector_type(2)));
union H2U { h2 h; unsigned u; };

__device__ __forceinline__ float fast_rcp(float v) {
    return __builtin_amdgcn_rcpf(v);
}

// ---- fused tiled kernel (stages + scales + packs inline, no workspace) ----
__global__ __launch_bounds__(1024, 2) void fab_tile(
    const float* __restrict__ x,
    const float* __restrict__ tangent,
    const float* __restrict__ sigmaD,
    const float* __restrict__ sigmaR,
    float* __restrict__ out)
{
    __shared__ uint2 tile[TW * TP];
    const int tiles_x = WW / TS;           // 32
    const int tiles_y = HH / TS;           // 24
    const int tpb = tiles_x * tiles_y;     // 768
    int tid = threadIdx.x;
    int bid = blockIdx.x;
    int b = bid / tpb;
    int tq = bid - b * tpb;
    int tyi = tq / tiles_x;
    int txi = tq - tyi * tiles_x;
    int tx0 = txi * TS, ty0 = tyi * TS;

    const float* xb = x + (size_t)b * 3 * HW;

    // stage halo window into LDS, scaling + packing inline.
    // Border-clamped staging -> border replication makes per-sample clamping
    // unnecessary (|sample displacement| <= 10 < RAD).
    for (int cI = tid; cI < TW * TW; cI += 1024) {
        int syy = cI / TW;
        int sxx = cI - syy * TW;
        int sgx = min(max(tx0 - RAD + sxx, 0), WW - 1);
        int sgy = min(max(ty0 - RAD + syy, 0), HH - 1);
        int g = sgy * WW + sgx;
        float a  = xb[g] * 100.0f;
        float c1 = xb[HW + g] * 254.0f;
        float c2 = xb[2 * HW + g] * 254.0f;
        H2U cv; cv.h = __builtin_amdgcn_cvt_pkrtz(c1, c2);
        uint2 v;
        v.x = __float_as_uint(a);
        v.y = cv.u;
        tile[syy * TP + sxx] = v;
    }
    __syncthreads();

    int lx = tid & (TS - 1);
    int ly = tid >> 5;
    int w = tx0 + lx, h = ty0 + ly;
    int p = h * WW + w;

    float tx = tangent[(size_t)b * 2 * HW + p];
    float ty = tangent[(size_t)b * 2 * HW + HW + p];
    float me = fmaxf(fabsf(tx), fabsf(ty));
    float ds = (me > 0.0f) ? fast_rcp(me) : 1.0f;
    float sD = sigmaD[b], sR = sigmaR[b];
    float half_step = 2.0f * sD;
    float nD = -fast_rcp(2.0f * sD * sD + F_EPS);
    float nR = -fast_rcp(2.0f * sR * sR + F_EPS);

    // exact (pre-scaled) center values
    uint2 ctex = tile[(ly + RAD) * TP + (lx + RAD)];
    float C0 = __uint_as_float(ctex.x);            // exact 100*c0
    float C1 = xb[HW + p] * 254.0f;                // exact 254*c1
    float C2 = xb[2 * HW + p] * 254.0f;            // exact 254*c2

    const f2 C0p = {C0, C0};
    const f2 C1p = {C1, C1};
    const f2 C2p = {C2, C2};
    const f2 one2 = {1.0f, 1.0f};
    const f2 nR2 = {nR, nR};

    // packed accumulators: halves = (sample+, sample-)
    f2 normp = {0.0f, 0.0f};
    f2 a0p = {0.0f, 0.0f};
    f2 a1p = {0.0f, 0.0f};
    f2 a2p = {0.0f, 0.0f};

    int bx = RAD - tx0, by = RAD - ty0;
    float wf = (float)w, hf = (float)h;

    // Gaussian recurrence: kD(n) = Q^(n^2), Q = exp(nD*ds*ds)
    float Q  = __expf(ds * ds * nD);
    float Q2 = Q * Q;
    float pw = Q;        // Q^(n^2), n=1
    float rq = Q2 * Q;   // Q^(2n+1), n=1

#pragma unroll
    for (int t = 0; t < NTAPS; ++t) {
        float itr1 = ds * (float)(2 * t + 1);
        float itr2 = ds * (float)(2 * t + 2);
        float kD1 = pw; pw *= rq; rq *= Q2;
        float kD2 = pw; pw *= rq; rq *= Q2;
        if (itr1 > half_step) continue;   // kernelD == 0 exactly -> no contribution
        float kernelD = kD1 + kD2;
        float itr_d = (itr1 * kD1 + itr2 * kD2) * fast_rcp(kernelD + F_EPS);
        float ox = itr_d * tx;
        float oy = itr_d * ty;

        // two samples (+offs, -offs) processed as packed f32 pairs
        f2 xpf2 = {wf + ox, wf - ox};
        f2 ypf2 = {hf + oy, hf - oy};
        float x0fa = floorf(xpf2.x), x0fb = floorf(xpf2.y);
        float y0fa = floorf(ypf2.x), y0fb = floorf(ypf2.y);
        f2 x0p = {x0fa, x0fb};
        f2 y0p = {y0fa, y0fb};
        f2 fx2 = xpf2 - x0p;
        f2 fy2 = ypf2 - y0p;
        int ja = (int)x0fa + bx, jb = (int)x0fb + bx;
        int ia = (int)y0fa + by, ib = (int)y0fb + by;
        const uint2* ca = tile + (ia * TP + ja);
        const uint2* cb = tile + (ib * TP + jb);
        uint2 ra00 = ca[0];
        uint2 ra01 = ca[1];
        uint2 ra10 = ca[TP];
        uint2 ra11 = ca[TP + 1];
        uint2 rb00 = cb[0];
        uint2 rb01 = cb[1];
        uint2 rb10 = cb[TP];
        uint2 rb11 = cb[TP + 1];

        f2 gx2 = one2 - fx2, gy2 = one2 - fy2;
        f2 w00 = gx2 * gy2, w01 = fx2 * gy2, w10 = gx2 * fy2, w11 = fx2 * fy2;

        // channel 0 (f32, packed across the sample pair)
        f2 q00 = {__uint_as_float(ra00.x), __uint_as_float(rb00.x)};
        f2 q01 = {__uint_as_float(ra01.x), __uint_as_float(rb01.x)};
        f2 q10 = {__uint_as_float(ra10.x), __uint_as_float(rb10.x)};
        f2 q11 = {__uint_as_float(ra11.x), __uint_as_float(rb11.x)};
        f2 s0p = w00 * q00 + w01 * q01 + w10 * q10 + w11 * q11;

        // channels 1,2 (packed fp16 per sample)
        H2U ua00, ua01, ua10, ua11, ub00, ub01, ub10, ub11;
        ua00.u = ra00.y; ua01.u = ra01.y; ua10.u = ra10.y; ua11.u = ra11.y;
        ub00.u = rb00.y; ub01.u = rb01.y; ub10.u = rb10.y; ub11.u = rb11.y;
        h2 Wa00 = __builtin_amdgcn_cvt_pkrtz(w00.x, w00.x);
        h2 Wa01 = __builtin_amdgcn_cvt_pkrtz(w01.x, w01.x);
        h2 Wa10 = __builtin_amdgcn_cvt_pkrtz(w10.x, w10.x);
        h2 Wa11 = __builtin_amdgcn_cvt_pkrtz(w11.x, w11.x);
        h2 Wb00 = __builtin_amdgcn_cvt_pkrtz(w00.y, w00.y);
        h2 Wb01 = __builtin_amdgcn_cvt_pkrtz(w01.y, w01.y);
        h2 Wb10 = __builtin_amdgcn_cvt_pkrtz(w10.y, w10.y);
        h2 Wb11 = __builtin_amdgcn_cvt_pkrtz(w11.y, w11.y);
        h2 sa = Wa00 * ua00.h + Wa01 * ua01.h + Wa10 * ua10.h + Wa11 * ua11.h;
        h2 sb = Wb00 * ub00.h + Wb01 * ub01.h + Wb10 * ub10.h + Wb11 * ub11.h;
        f2 s1p = {(float)sa.x, (float)sb.x};
        f2 s2p = {(float)sa.y, (float)sb.y};

        f2 cc0 = s0p - C0p;
        f2 cc1 = s1p - C1p;
        f2 cc2 = s2p - C2p;
        f2 e2p = cc0 * cc0 + cc1 * cc1 + cc2 * cc2;
        f2 e2n = e2p * nR2;
        f2 kEp = {__expf(e2n.x), __expf(e2n.y)};
        f2 kDp = {kernelD, kernelD};
        f2 wgtp = kEp * kDp;
        normp += wgtp;
        a0p += wgtp * s0p;
        a1p += wgtp * s1p;
        a2p += wgtp * s2p;
    }

    float norm = 1.0f + normp.x + normp.y;
    float a0 = C0 + a0p.x + a0p.y;
    float a1 = C1 + a1p.x + a1p.y;
    float a2 = C2 + a2p.x + a2p.y;

    float inv = fast_rcp(norm);
    size_t ob = (size_t)b * 3 * HW;
    out[ob + p]          = a0 * inv * 0.01f;
    out[ob + HW + p]     = a1 * inv * (1.0f / 254.0f);
    out[ob + 2 * HW + p] = a2 * inv * (1.0f / 254.0f);
}

extern "C" void kernel_launch(void* const* d_in, const int* in_sizes, int n_in,
                              void* d_out, int out_size, void* d_ws, size_t ws_size,
                              hipStream_t stream) {
    const float* x = (const float*)d_in[0];
    const float* tangent = (const float*)d_in[1];
    const float* sigmaD = (const float*)d_in[2];
    const float* sigmaR = (const float*)d_in[3];
    float* out = (float*)d_out;

    int bs = in_sizes[2];           // sigmaD has one entry per batch
    int tpb = (WW / TS) * (HH / TS);
    fab_tile<<<bs * tpb, 1024, 0, stream>>>(x, tangent, sigmaD, sigmaR, out);
}

// Round 8
// 34.774 us; speedup vs baseline: 4.5051x; 1.1801x over previous
//
#include <hip/hip_runtime.h>
#include <hip/hip_fp16.h>
#include <math.h>

#define HH 768
#define WW 1024
#define HW (HH * WW)
#define NTAPS 5
#define F_EPS 1.1920929e-07f

#define TS   32            // tile size (pixels)
#define RAD  10            // halo radius: |sample disp| < 10 strictly (itr_d < itr2 <= 10)
#define ROWS 53            // staged rows:    r in [0, 52]  (floor range [-10,+9] + corner +1)
#define COLS 53            // staged columns: c in [0, 52]
#define TP   54            // padded LDS row stride (dwords); read2 offsets TP,TP+1 <= 255 ok

typedef __fp16 h2 __attribute__((ext_vector_type(2)));
typedef float  f2 __attribute__((ext_vector_type(2)));
union H2U { h2 h; unsigned u; };

__device__ __forceinline__ float fast_rcp(float v) {
    return __builtin_amdgcn_rcpf(v);
}
__device__ __forceinline__ h2 as_h2(unsigned u) { H2U t; t.u = u; return t.h; }

// ---- fused tiled kernel: split 4B texel arrays, ds_read2-friendly ----------
__global__ __launch_bounds__(1024, 2) void fab_tile(
    const float* __restrict__ x,
    const float* __restrict__ tangent,
    const float* __restrict__ sigmaD,
    const float* __restrict__ sigmaR,
    float* __restrict__ out)
{
    __shared__ unsigned tileA[ROWS * TP];  // fp16 pair (100*c0[x], 100*c0[x+1])
    __shared__ unsigned tileB[ROWS * TP];  // fp16 pair (254*c1,    254*c2)

    const int tiles_x = WW / TS;           // 32
    const int tiles_y = HH / TS;           // 24
    const int tpb = tiles_x * tiles_y;     // 768
    int tid = threadIdx.x;
    int bid = blockIdx.x;
    int b = bid / tpb;
    int tq = bid - b * tpb;
    int tyi = tq / tiles_x;
    int txi = tq - tyi * tiles_x;
    int tx0 = txi * TS, ty0 = tyi * TS;

    const float* xb = x + (size_t)b * 3 * HW;

    // stage halo window (border-clamped -> per-sample clamping unnecessary)
    for (int cI = tid; cI < ROWS * COLS; cI += 1024) {
        int syy = cI / COLS;               // const divisor -> magic mul
        int sxx = cI - syy * COLS;
        int wx = tx0 - RAD + sxx;
        int sgx  = min(max(wx, 0), WW - 1);
        int sgx1 = min(max(wx + 1, 0), WW - 1);
        int sgy = min(max(ty0 - RAD + syy, 0), HH - 1);
        int g = sgy * WW;
        float a0v = xb[g + sgx]  * 100.0f;
        float a1v = xb[g + sgx1] * 100.0f;
        float c1v = xb[HW + g + sgx]     * 254.0f;
        float c2v = xb[2 * HW + g + sgx] * 254.0f;
        H2U pa; pa.h = __builtin_amdgcn_cvt_pkrtz(a0v, a1v);
        H2U pb; pb.h = __builtin_amdgcn_cvt_pkrtz(c1v, c2v);
        int o = syy * TP + sxx;
        tileA[o] = pa.u;
        tileB[o] = pb.u;
    }
    __syncthreads();

    int lx = tid & (TS - 1);
    int ly = tid >> 5;
    int w = tx0 + lx, h = ty0 + ly;
    int p = h * WW + w;

    float tx = tangent[(size_t)b * 2 * HW + p];
    float ty = tangent[(size_t)b * 2 * HW + HW + p];
    float me = fmaxf(fabsf(tx), fabsf(ty));
    float ds = (me > 0.0f) ? fast_rcp(me) : 1.0f;
    float sD = sigmaD[b], sR = sigmaR[b];
    float half_step = 2.0f * sD;
    float nD = -fast_rcp(2.0f * sD * sD + F_EPS);
    float nR = -fast_rcp(2.0f * sR * sR + F_EPS);

    // exact (pre-scaled) center values from global (L1-hot after staging)
    float C0 = xb[p] * 100.0f;
    float C1 = xb[HW + p] * 254.0f;
    float C2 = xb[2 * HW + p] * 254.0f;

    const f2 C0p = {C0, C0};
    const f2 C1p = {C1, C1};
    const f2 C2p = {C2, C2};
    const f2 one2 = {1.0f, 1.0f};
    const f2 nR2 = {nR, nR};

    f2 normp = {0.0f, 0.0f};
    f2 a0p = {0.0f, 0.0f};
    f2 a1p = {0.0f, 0.0f};
    f2 a2p = {0.0f, 0.0f};

    int bx = RAD - tx0, by = RAD - ty0;
    float wf = (float)w, hf = (float)h;

    // Gaussian recurrence: kD(n) = Q^(n^2), Q = exp(nD*ds*ds)
    float Q  = __expf(ds * ds * nD);
    float Q2 = Q * Q;
    float pw = Q;        // Q^(n^2), n=1
    float rq = Q2 * Q;   // Q^(2n+1), n=1

#pragma unroll
    for (int t = 0; t < NTAPS; ++t) {
        float itr1 = ds * (float)(2 * t + 1);
        float itr2 = ds * (float)(2 * t + 2);
        float kD1 = pw; pw *= rq; rq *= Q2;
        float kD2 = pw; pw *= rq; rq *= Q2;
        if (itr1 > half_step) continue;   // kernelD == 0 exactly -> no contribution
        float kernelD = kD1 + kD2;
        float itr_d = (itr1 * kD1 + itr2 * kD2) * fast_rcp(kernelD + F_EPS);
        float ox = itr_d * tx;
        float oy = itr_d * ty;

        f2 xpf2 = {wf + ox, wf - ox};
        f2 ypf2 = {hf + oy, hf - oy};
        float x0fa = floorf(xpf2.x), x0fb = floorf(xpf2.y);
        float y0fa = floorf(ypf2.x), y0fb = floorf(ypf2.y);
        f2 x0p = {x0fa, x0fb};
        f2 y0p = {y0fa, y0fb};
        f2 fx2 = xpf2 - x0p;
        f2 fy2 = ypf2 - y0p;
        int ja = (int)x0fa + bx, jb = (int)x0fb + bx;
        int ia = (int)y0fa + by, ib = (int)y0fb + by;
        int i0a = ia * TP + ja;
        int i0b = ib * TP + jb;

        // 3 LDS transactions per sample (ds_read2_b32-mergeable pairs)
        unsigned At_a = tileA[i0a];
        unsigned Ab_a = tileA[i0a + TP];
        unsigned B00a = tileB[i0a];
        unsigned B01a = tileB[i0a + 1];
        unsigned B10a = tileB[i0a + TP];
        unsigned B11a = tileB[i0a + TP + 1];

        unsigned At_b = tileA[i0b];
        unsigned Ab_b = tileA[i0b + TP];
        unsigned B00b = tileB[i0b];
        unsigned B01b = tileB[i0b + 1];
        unsigned B10b = tileB[i0b + TP];
        unsigned B11b = tileB[i0b + TP + 1];

        f2 gx2 = one2 - fx2, gy2 = one2 - fy2;
        f2 w00 = gx2 * gy2, w01 = fx2 * gy2, w10 = gx2 * fy2, w11 = fx2 * fy2;

        // ---- sample a ----
        h2 WtA = __builtin_amdgcn_cvt_pkrtz(w00.x, w01.x);
        h2 WbA = __builtin_amdgcn_cvt_pkrtz(w10.x, w11.x);
        h2 m0a = as_h2(At_a) * WtA + as_h2(Ab_a) * WbA;   // (w00q00+w10q10, w01q01+w11q11)
        float s0a = (float)m0a.x + (float)m0a.y;
        h2 s12a = __builtin_amdgcn_cvt_pkrtz(w00.x, w00.x) * as_h2(B00a)
                + __builtin_amdgcn_cvt_pkrtz(w01.x, w01.x) * as_h2(B01a)
                + __builtin_amdgcn_cvt_pkrtz(w10.x, w10.x) * as_h2(B10a)
                + __builtin_amdgcn_cvt_pkrtz(w11.x, w11.x) * as_h2(B11a);

        // ---- sample b ----
        h2 WtB = __builtin_amdgcn_cvt_pkrtz(w00.y, w01.y);
        h2 WbB = __builtin_amdgcn_cvt_pkrtz(w10.y, w11.y);
        h2 m0b = as_h2(At_b) * WtB + as_h2(Ab_b) * WbB;
        float s0b = (float)m0b.x + (float)m0b.y;
        h2 s12b = __builtin_amdgcn_cvt_pkrtz(w00.y, w00.y) * as_h2(B00b)
                + __builtin_amdgcn_cvt_pkrtz(w01.y, w01.y) * as_h2(B01b)
                + __builtin_amdgcn_cvt_pkrtz(w10.y, w10.y) * as_h2(B10b)
                + __builtin_amdgcn_cvt_pkrtz(w11.y, w11.y) * as_h2(B11b);

        f2 s0p = {s0a, s0b};
        f2 s1p = {(float)s12a.x, (float)s12b.x};
        f2 s2p = {(float)s12a.y, (float)s12b.y};

        f2 cc0 = s0p - C0p;
        f2 cc1 = s1p - C1p;
        f2 cc2 = s2p - C2p;
        f2 e2p = cc0 * cc0 + cc1 * cc1 + cc2 * cc2;
        f2 e2n = e2p * nR2;
        f2 kEp = {__expf(e2n.x), __expf(e2n.y)};
        f2 kDp = {kernelD, kernelD};
        f2 wgtp = kEp * kDp;
        normp += wgtp;
        a0p += wgtp * s0p;
        a1p += wgtp * s1p;
        a2p += wgtp * s2p;
    }

    float norm = 1.0f + normp.x + normp.y;
    float a0 = C0 + a0p.x + a0p.y;
    float a1 = C1 + a1p.x + a1p.y;
    float a2 = C2 + a2p.x + a2p.y;

    float inv = fast_rcp(norm);
    size_t ob = (size_t)b * 3 * HW;
    out[ob + p]          = a0 * inv * 0.01f;
    out[ob + HW + p]     = a1 * inv * (1.0f / 254.0f);
    out[ob + 2 * HW + p] = a2 * inv * (1.0f / 254.0f);
}

extern "C" void kernel_launch(void* const* d_in, const int* in_sizes, int n_in,
                              void* d_out, int out_size, void* d_ws, size_t ws_size,
                              hipStream_t stream) {
    const float* x = (const float*)d_in[0];
    const float* tangent = (const float*)d_in[1];
    const float* sigmaD = (const float*)d_in[2];
    const float* sigmaR = (const float*)d_in[3];
    float* out = (float*)d_out;

    int bs = in_sizes[2];           // sigmaD has one entry per batch
    int tpb = (WW / TS) * (HH / TS);
    fab_tile<<<bs * tpb, 1024, 0, stream>>>(x, tangent, sigmaD, sigmaR, out);
}

// Round 9
// 31.694 us; speedup vs baseline: 4.9429x; 1.0972x over previous
//
#include <hip/hip_runtime.h>
#include <hip/hip_fp16.h>
#include <math.h>

#define HH 768
#define WW 1024
#define HW (HH * WW)
#define NTAPS 5
#define F_EPS 1.1920929e-07f

#define TS   32            // tile size (pixels)
#define RAD  10            // halo radius: |sample disp| < 10 strictly
#define ROWS 53            // staged rows
#define COLS 53            // staged cols
#define TP   54            // padded LDS row stride (dwords)

typedef __fp16 h2 __attribute__((ext_vector_type(2)));
typedef float  f2 __attribute__((ext_vector_type(2)));
union H2U { h2 h; unsigned u; };

__device__ __forceinline__ float fast_rcp(float v) {
    return __builtin_amdgcn_rcpf(v);
}
__device__ __forceinline__ h2 as_h2(unsigned u) { H2U t; t.u = u; return t.h; }

__global__ __launch_bounds__(1024, 2) void fab_tile(
    const float* __restrict__ x,
    const float* __restrict__ tangent,
    const float* __restrict__ sigmaD,
    const float* __restrict__ sigmaR,
    float* __restrict__ out)
{
    __shared__ unsigned tileA[ROWS * TP];  // fp16 pair (100*c0[x], 100*c0[x+1])
    __shared__ unsigned tileB[ROWS * TP];  // fp16 pair (254*c1,    254*c2)

    const int tiles_x = WW / TS;           // 32
    const int tiles_y = HH / TS;           // 24
    const int tpb = tiles_x * tiles_y;     // 768
    int tid = threadIdx.x;
    int bid = blockIdx.x;
    int b = bid / tpb;
    int tq = bid - b * tpb;
    int tyi = tq / tiles_x;
    int txi = tq - tyi * tiles_x;
    int tx0 = txi * TS, ty0 = tyi * TS;

    const float* xb = x + (size_t)b * 3 * HW;

    // stage halo window (border-clamped -> per-sample clamping unnecessary)
    for (int cI = tid; cI < ROWS * COLS; cI += 1024) {
        int syy = cI / COLS;
        int sxx = cI - syy * COLS;
        int wx = tx0 - RAD + sxx;
        int sgx  = min(max(wx, 0), WW - 1);
        int sgx1 = min(max(wx + 1, 0), WW - 1);
        int sgy = min(max(ty0 - RAD + syy, 0), HH - 1);
        int g = sgy * WW;
        float a0v = xb[g + sgx]  * 100.0f;
        float a1v = xb[g + sgx1] * 100.0f;
        float c1v = xb[HW + g + sgx]     * 254.0f;
        float c2v = xb[2 * HW + g + sgx] * 254.0f;
        H2U pa; pa.h = __builtin_amdgcn_cvt_pkrtz(a0v, a1v);
        H2U pb; pb.h = __builtin_amdgcn_cvt_pkrtz(c1v, c2v);
        int o = syy * TP + sxx;
        tileA[o] = pa.u;
        tileB[o] = pb.u;
    }
    __syncthreads();

    int lx = tid & (TS - 1);
    int ly = tid >> 5;
    int w = tx0 + lx, h = ty0 + ly;
    int p = h * WW + w;

    float tx = tangent[(size_t)b * 2 * HW + p];
    float ty = tangent[(size_t)b * 2 * HW + HW + p];
    float me = fmaxf(fabsf(tx), fabsf(ty));
    float ds = (me > 0.0f) ? fast_rcp(me) : 1.0f;
    float sD = sigmaD[b], sR = sigmaR[b];
    float half_step = 2.0f * sD;
    float nD = -fast_rcp(2.0f * sD * sD + F_EPS);
    float nR = -fast_rcp(2.0f * sR * sR + F_EPS);

    // exact (pre-scaled) center values from global (L1-hot after staging)
    float C0 = xb[p] * 100.0f;
    float C1 = xb[HW + p] * 254.0f;
    float C2 = xb[2 * HW + p] * 254.0f;

    const f2 C0p = {C0, C0};
    const f2 C1p = {C1, C1};
    const f2 C2p = {C2, C2};
    const f2 nR2 = {nR, nR};

    f2 normp = {0.0f, 0.0f};
    f2 a0p = {0.0f, 0.0f};
    f2 a1p = {0.0f, 0.0f};
    f2 a2p = {0.0f, 0.0f};

    // tile-local index bases for the +sample (a) and the mirrored -sample (b)
    int ibase_a = (RAD + ly) * TP + (RAD + lx);
    int ibase_b = ibase_a - TP - 1;

    // Gaussian recurrence: kD(n) = Q^(n^2), Q = exp(nD*ds*ds)
    float Q  = __expf(ds * ds * nD);
    float Q2 = Q * Q;
    float pw = Q;        // Q^(n^2), n=1
    float rq = Q2 * Q;   // Q^(2n+1), n=1

#pragma unroll
    for (int t = 0; t < NTAPS; ++t) {
        float itr1 = ds * (float)(2 * t + 1);
        float itr2 = ds * (float)(2 * t + 2);
        float kD1 = pw; pw *= rq; rq *= Q2;
        float kD2 = pw; pw *= rq; rq *= Q2;
        if (itr1 > half_step) continue;   // kernelD == 0 exactly -> no contribution
        float kernelD = kD1 + kD2;
        float itr_d = (itr1 * kD1 + itr2 * kD2) * fast_rcp(kernelD + F_EPS);
        float ox = itr_d * tx;
        float oy = itr_d * ty;

        // shared floor/frac: floor(w+ox) = w+floor(ox); floor(w-ox) = w-floor(ox)-1
        float fox = floorf(ox), foy = floorf(oy);
        float f_x = ox - fox,   f_y = oy - foy;
        int iox = (int)fox, ioy = (int)foy;
        int d = ioy * TP + iox;
        int i0a = ibase_a + d;
        int i0b = ibase_b - d;

        // LDS reads: 3 ds_read2-mergeable pairs per sample
        unsigned At_a = tileA[i0a];
        unsigned Ab_a = tileA[i0a + TP];
        unsigned B00a = tileB[i0a];
        unsigned B01a = tileB[i0a + 1];
        unsigned B10a = tileB[i0a + TP];
        unsigned B11a = tileB[i0a + TP + 1];
        unsigned At_b = tileA[i0b];
        unsigned Ab_b = tileA[i0b + TP];
        unsigned B00b = tileB[i0b];
        unsigned B01b = tileB[i0b + 1];
        unsigned B10b = tileB[i0b + TP];
        unsigned B11b = tileB[i0b + TP + 1];

        // one weight set, shared; b-sample weights are a permutation of a's
        float gxa = 1.0f - f_x, gya = 1.0f - f_y;
        float w00 = gxa * gya, w01 = f_x * gya, w10 = gxa * f_y, w11 = f_x * f_y;
        h2 Wt  = __builtin_amdgcn_cvt_pkrtz(w00, w01);
        h2 Wb  = __builtin_amdgcn_cvt_pkrtz(w10, w11);
        h2 WtR = __builtin_shufflevector(Wb, Wb, 1, 0);   // (w11, w10) = b top
        h2 WbR = __builtin_shufflevector(Wt, Wt, 1, 0);   // (w01, w00) = b bottom
        h2 W00 = __builtin_amdgcn_cvt_pkrtz(w00, w00);
        h2 W01 = __builtin_amdgcn_cvt_pkrtz(w01, w01);
        h2 W10 = __builtin_amdgcn_cvt_pkrtz(w10, w10);
        h2 W11 = __builtin_amdgcn_cvt_pkrtz(w11, w11);

        // sample a
        h2 m0a = as_h2(At_a) * Wt + as_h2(Ab_a) * Wb;
        float s0a = (float)m0a.x + (float)m0a.y;
        h2 s12a = W00 * as_h2(B00a) + W01 * as_h2(B01a)
                + W10 * as_h2(B10a) + W11 * as_h2(B11a);

        // sample b (permuted weights)
        h2 m0b = as_h2(At_b) * WtR + as_h2(Ab_b) * WbR;
        float s0b = (float)m0b.x + (float)m0b.y;
        h2 s12b = W11 * as_h2(B00b) + W10 * as_h2(B01b)
                + W01 * as_h2(B10b) + W00 * as_h2(B11b);

        f2 s0p = {s0a, s0b};
        f2 s1p = {(float)s12a.x, (float)s12b.x};
        f2 s2p = {(float)s12a.y, (float)s12b.y};

        f2 cc0 = s0p - C0p;
        f2 cc1 = s1p - C1p;
        f2 cc2 = s2p - C2p;
        f2 e2p = cc0 * cc0 + cc1 * cc1 + cc2 * cc2;
        f2 e2n = e2p * nR2;
        f2 kEp = {__expf(e2n.x), __expf(e2n.y)};
        f2 kDp = {kernelD, kernelD};
        f2 wgtp = kEp * kDp;
        normp += wgtp;
        a0p += wgtp * s0p;
        a1p += wgtp * s1p;
        a2p += wgtp * s2p;
    }

    float norm = 1.0f + normp.x + normp.y;
    float a0 = C0 + a0p.x + a0p.y;
    float a1 = C1 + a1p.x + a1p.y;
    float a2 = C2 + a2p.x + a2p.y;

    float inv = fast_rcp(norm);
    size_t ob = (size_t)b * 3 * HW;
    out[ob + p]          = a0 * inv * 0.01f;
    out[ob + HW + p]     = a1 * inv * (1.0f / 254.0f);
    out[ob + 2 * HW + p] = a2 * inv * (1.0f / 254.0f);
}

extern "C" void kernel_launch(void* const* d_in, const int* in_sizes, int n_in,
                              void* d_out, int out_size, void* d_ws, size_t ws_size,
                              hipStream_t stream) {
    const float* x = (const float*)d_in[0];
    const float* tangent = (const float*)d_in[1];
    const float* sigmaD = (const float*)d_in[2];
    const float* sigmaR = (const float*)d_in[3];
    float* out = (float*)d_out;

    int bs = in_sizes[2];           // sigmaD has one entry per batch
    int tpb = (WW / TS) * (HH / TS);
    fab_tile<<<bs * tpb, 1024, 0, stream>>>(x, tangent, sigmaD, sigmaR, out);
}

// Round 10
// 31.655 us; speedup vs baseline: 4.9490x; 1.0012x over previous
//
#include <hip/hip_runtime.h>
#include <hip/hip_fp16.h>
#include <math.h>

#define HH 768
#define WW 1024
#define HW (HH * WW)
#define NTAPS 5
#define F_EPS 1.1920929e-07f
#define LOG2E 1.44269504f

#define TS   32            // tile size (pixels)
#define RAD  10            // halo radius: |sample disp| < 10 strictly
#define ROWS 53            // staged rows
#define COLS 53            // staged cols
#define TP   54            // padded LDS row stride (texels); read2 offset TP<=255 ok

typedef __fp16 h2 __attribute__((ext_vector_type(2)));
typedef float  f2 __attribute__((ext_vector_type(2)));
union H2U { h2 h; unsigned u; };

__device__ __forceinline__ float fast_rcp(float v) {
    return __builtin_amdgcn_rcpf(v);
}
__device__ __forceinline__ h2 as_h2(unsigned u) { H2U t; t.u = u; return t.h; }

__global__ __launch_bounds__(1024, 2) void fab_tile(
    const float* __restrict__ x,
    const float* __restrict__ tangent,
    const float* __restrict__ sigmaD,
    const float* __restrict__ sigmaR,
    float* __restrict__ out)
{
    // interleaved texel: .x = h2(100*c0[x], 100*c0[x+1]), .y = h2(254*c1, 254*c2)
    __shared__ uint2 tileT[ROWS * TP];

    const int tiles_x = WW / TS;           // 32
    const int tiles_y = HH / TS;           // 24
    const int tpb = tiles_x * tiles_y;     // 768
    int tid = threadIdx.x;
    int bid = blockIdx.x;
    int b = bid / tpb;
    int tq = bid - b * tpb;
    int tyi = tq / tiles_x;
    int txi = tq - tyi * tiles_x;
    int tx0 = txi * TS, ty0 = tyi * TS;

    const float* xb = x + (size_t)b * 3 * HW;

    // stage halo window (border-clamped -> per-sample clamping unnecessary)
    for (int cI = tid; cI < ROWS * COLS; cI += 1024) {
        int syy = cI / COLS;
        int sxx = cI - syy * COLS;
        int wx = tx0 - RAD + sxx;
        int sgx  = min(max(wx, 0), WW - 1);
        int sgx1 = min(max(wx + 1, 0), WW - 1);
        int sgy = min(max(ty0 - RAD + syy, 0), HH - 1);
        int g = sgy * WW;
        float a0v = xb[g + sgx]  * 100.0f;
        float a1v = xb[g + sgx1] * 100.0f;
        float c1v = xb[HW + g + sgx]     * 254.0f;
        float c2v = xb[2 * HW + g + sgx] * 254.0f;
        H2U pa; pa.h = __builtin_amdgcn_cvt_pkrtz(a0v, a1v);
        H2U pb; pb.h = __builtin_amdgcn_cvt_pkrtz(c1v, c2v);
        uint2 v; v.x = pa.u; v.y = pb.u;
        tileT[syy * TP + sxx] = v;
    }
    __syncthreads();

    int lx = tid & (TS - 1);
    int ly = tid >> 5;
    int w = tx0 + lx, h = ty0 + ly;
    int p = h * WW + w;

    float tx = tangent[(size_t)b * 2 * HW + p];
    float ty = tangent[(size_t)b * 2 * HW + HW + p];
    float me = fmaxf(fabsf(tx), fabsf(ty));
    float ds = (me > 0.0f) ? fast_rcp(me) : 1.0f;
    float sD = sigmaD[b], sR = sigmaR[b];
    float half_step = 2.0f * sD;
    // exp2-domain gaussian constants (log2e folded in)
    float nD = -fast_rcp(2.0f * sD * sD + F_EPS) * LOG2E;
    float nR = -fast_rcp(2.0f * sR * sR + F_EPS) * LOG2E;

    // exact (pre-scaled) center values from global (L1/L2-hot after staging)
    float C0 = xb[p] * 100.0f;
    float C1 = xb[HW + p] * 254.0f;
    float C2 = xb[2 * HW + p] * 254.0f;

    const f2 C0p = {C0, C0};
    const f2 C1p = {C1, C1};
    const f2 C2p = {C2, C2};
    const f2 nR2 = {nR, nR};

    f2 normp = {0.0f, 0.0f};
    f2 a0p = {0.0f, 0.0f};
    f2 a1p = {0.0f, 0.0f};
    f2 a2p = {0.0f, 0.0f};

    // tile-local index bases for the +sample (a) and mirrored -sample (b)
    int ibase_a = (RAD + ly) * TP + (RAD + lx);
    int ibase_b = ibase_a - TP - 1;

    // Gaussian recurrence in exp2 domain: kD(n) = Q^(n^2), Q = 2^(nD*ds*ds)
    float Q  = __builtin_amdgcn_exp2f(ds * ds * nD);
    float Q2 = Q * Q;
    float pw = Q;        // Q^(n^2), n=1
    float rq = Q2 * Q;   // Q^(2n+1), n=1

    const unsigned* td = (const unsigned*)tileT;

#pragma unroll
    for (int t = 0; t < NTAPS; ++t) {
        float itr1 = ds * (float)(2 * t + 1);
        float itr2 = ds * (float)(2 * t + 2);
        float kD1 = pw; pw *= rq; rq *= Q2;
        float kD2 = pw; pw *= rq; rq *= Q2;
        if (itr1 > half_step) continue;   // kernelD == 0 exactly -> no contribution
        float kernelD = kD1 + kD2;
        float itr_d = (itr1 * kD1 + itr2 * kD2) * fast_rcp(kernelD + F_EPS);
        float ox = itr_d * tx;
        float oy = itr_d * ty;

        // shared floor/frac: floor(w+ox) = w+floor(ox); floor(w-ox) = w-floor(ox)-1
        float fox = floorf(ox), foy = floorf(oy);
        float f_x = ox - fox,   f_y = oy - foy;
        int iox = (int)fox, ioy = (int)foy;
        int d = ioy * TP + iox;
        int i0a = ibase_a + d;
        int i0b = ibase_b - d;

        // 2 LDS instructions per sample:
        //   ds_read2_b64 {0, TP}   -> texels (i), (i+TP)        (A + left B's)
        //   ds_read2_b32 {3, 2TP+3}-> right-corner B's (i+1), (i+TP+1)
        uint2 Ta  = tileT[i0a];
        uint2 Tta = tileT[i0a + TP];
        unsigned Bra = td[2 * i0a + 3];
        unsigned Bba = td[2 * i0a + 2 * TP + 3];
        uint2 Tb  = tileT[i0b];
        uint2 Ttb = tileT[i0b + TP];
        unsigned Brb = td[2 * i0b + 3];
        unsigned Bbb = td[2 * i0b + 2 * TP + 3];

        // one weight set, shared; b-sample weights are a permutation of a's
        float gxa = 1.0f - f_x, gya = 1.0f - f_y;
        float w00 = gxa * gya, w01 = f_x * gya, w10 = gxa * f_y, w11 = f_x * f_y;
        h2 Wt  = __builtin_amdgcn_cvt_pkrtz(w00, w01);
        h2 Wb  = __builtin_amdgcn_cvt_pkrtz(w10, w11);
        h2 WtR = __builtin_shufflevector(Wb, Wb, 1, 0);   // (w11, w10) = b top
        h2 WbR = __builtin_shufflevector(Wt, Wt, 1, 0);   // (w01, w00) = b bottom
        h2 W00 = __builtin_amdgcn_cvt_pkrtz(w00, w00);
        h2 W01 = __builtin_amdgcn_cvt_pkrtz(w01, w01);
        h2 W10 = __builtin_amdgcn_cvt_pkrtz(w10, w10);
        h2 W11 = __builtin_amdgcn_cvt_pkrtz(w11, w11);

        // sample a
        h2 m0a = as_h2(Ta.x) * Wt + as_h2(Tta.x) * Wb;
        float s0a = (float)m0a.x + (float)m0a.y;
        h2 s12a = W00 * as_h2(Ta.y) + W01 * as_h2(Bra)
                + W10 * as_h2(Tta.y) + W11 * as_h2(Bba);

        // sample b (permuted weights)
        h2 m0b = as_h2(Tb.x) * WtR + as_h2(Ttb.x) * WbR;
        float s0b = (float)m0b.x + (float)m0b.y;
        h2 s12b = W11 * as_h2(Tb.y) + W10 * as_h2(Brb)
                + W01 * as_h2(Ttb.y) + W00 * as_h2(Bbb);

        f2 s0p = {s0a, s0b};
        f2 s1p = {(float)s12a.x, (float)s12b.x};
        f2 s2p = {(float)s12a.y, (float)s12b.y};

        f2 cc0 = s0p - C0p;
        f2 cc1 = s1p - C1p;
        f2 cc2 = s2p - C2p;
        f2 e2p = cc0 * cc0 + cc1 * cc1 + cc2 * cc2;
        f2 e2n = e2p * nR2;
        f2 kEp = {__builtin_amdgcn_exp2f(e2n.x), __builtin_amdgcn_exp2f(e2n.y)};
        f2 kDp = {kernelD, kernelD};
        f2 wgtp = kEp * kDp;
        normp += wgtp;
        a0p += wgtp * s0p;
        a1p += wgtp * s1p;
        a2p += wgtp * s2p;
    }

    float norm = 1.0f + normp.x + normp.y;
    float a0 = C0 + a0p.x + a0p.y;
    float a1 = C1 + a1p.x + a1p.y;
    float a2 = C2 + a2p.x + a2p.y;

    float inv = fast_rcp(norm);
    size_t ob = (size_t)b * 3 * HW;
    out[ob + p]          = a0 * inv * 0.01f;
    out[ob + HW + p]     = a1 * inv * (1.0f / 254.0f);
    out[ob + 2 * HW + p] = a2 * inv * (1.0f / 254.0f);
}

extern "C" void kernel_launch(void* const* d_in, const int* in_sizes, int n_in,
                              void* d_out, int out_size, void* d_ws, size_t ws_size,
                              hipStream_t stream) {
    const float* x = (const float*)d_in[0];
    const float* tangent = (const float*)d_in[1];
    const float* sigmaD = (const float*)d_in[2];
    const float* sigmaR = (const float*)d_in[3];
    float* out = (float*)d_out;

    int bs = in_sizes[2];           // sigmaD has one entry per batch
    int tpb = (WW / TS) * (HH / TS);
    fab_tile<<<bs * tpb, 1024, 0, stream>>>(x, tangent, sigmaD, sigmaR, out);
}